// Round 2
// baseline (692.145 us; speedup 1.0000x reference)
//
#include <hip/hip_runtime.h>
#include <stdint.h>

#define NN 100000
#define DIM 128
#define RR 8
#define BB 4
#define EE 1600000
#define EPR 200000
#define SLOPE 0.2f

typedef __attribute__((ext_vector_type(8))) short short8;
typedef __attribute__((ext_vector_type(4))) float f32x4;

__device__ __forceinline__ unsigned short f2bf(float f) {
    unsigned u = __float_as_uint(f);
    unsigned r = (u + 0x7FFFu + ((u >> 16) & 1u)) >> 16;  // RNE
    return (unsigned short)r;
}
// monotone float->uint key for atomicMax (init 0 acts as -inf sentinel)
__device__ __forceinline__ unsigned fkey(float f) {
    unsigned b = __float_as_uint(f);
    return (b & 0x80000000u) ? ~b : (b | 0x80000000u);
}
__device__ __forceinline__ float funkey(unsigned k) {
    unsigned b = (k & 0x80000000u) ? (k & 0x7FFFFFFFu) : ~k;
    return __uint_as_float(b);
}

// --- 1. W[r] = sum_b att[r,b]*basis[b]; store W^T bf16; fold attention vecs:
//        wsrc[r][i] = sum_o W[r][i][o]*a_src[r][o]  (so scores skip Wh entirely)
__global__ void k_prep(const float* __restrict__ att, const float* __restrict__ basis,
                       const float* __restrict__ attention,
                       unsigned short* __restrict__ wt, float* __restrict__ wsrc,
                       float* __restrict__ wdst) {
    int r = blockIdx.x;
    int i = threadIdx.x;  // 0..127
    float a[BB];
#pragma unroll
    for (int b = 0; b < BB; ++b) a[b] = att[r * BB + b];
    const float* asrc = attention + r * 2 * DIM;
    const float* adst = asrc + DIM;
    float ws = 0.f, wd = 0.f;
    for (int o = 0; o < DIM; ++o) {
        float w = 0.f;
#pragma unroll
        for (int b = 0; b < BB; ++b) w += a[b] * basis[(b * DIM + i) * DIM + o];
        wt[(r * DIM + o) * DIM + i] = f2bf(w);  // transposed [o][i]
        ws += w * asrc[o];
        wd += w * adst[o];
    }
    wsrc[r * DIM + i] = ws;
    wdst[r * DIM + i] = wd;
}

// --- 2. scores s_src/s_dst (f32) + X -> bf16 conversion. One wave per node.
__global__ __launch_bounds__(256) void k_scores(const float* __restrict__ x,
        const float* __restrict__ wsrc, const float* __restrict__ wdst,
        float* __restrict__ ssrc, float* __restrict__ sdst, unsigned* __restrict__ xb) {
    __shared__ float sw[2 * RR * DIM];
    for (int t = threadIdx.x; t < RR * DIM; t += 256) {
        sw[t] = wsrc[t];
        sw[RR * DIM + t] = wdst[t];
    }
    __syncthreads();
    int wave = threadIdx.x >> 6, lane = threadIdx.x & 63;
    int n = blockIdx.x * 4 + wave;
    float2 xv = *(const float2*)(x + (size_t)n * DIM + lane * 2);
    xb[n * 64 + lane] = (unsigned)f2bf(xv.x) | ((unsigned)f2bf(xv.y) << 16);
#pragma unroll
    for (int r = 0; r < RR; ++r) {
        float ps = xv.x * sw[r * DIM + 2 * lane] + xv.y * sw[r * DIM + 2 * lane + 1];
        float pd = xv.x * sw[RR * DIM + r * DIM + 2 * lane] +
                   xv.y * sw[RR * DIM + r * DIM + 2 * lane + 1];
#pragma unroll
        for (int o = 32; o > 0; o >>= 1) {
            ps += __shfl_xor(ps, o);
            pd += __shfl_xor(pd, o);
        }
        if (lane == 0) { ssrc[r * NN + n] = ps; sdst[r * NN + n] = pd; }
    }
}

// --- 3. Wh[r][n][o] (bf16) = X @ W[r].  MFMA 16x16x32 bf16, swapped operands:
//     A = W^T tile from LDS (M dim = o), B = X rows from global (N dim = n).
__global__ __launch_bounds__(256) void k_gemm(const unsigned short* __restrict__ wt,
        const unsigned short* __restrict__ xb, unsigned short* __restrict__ wh) {
    __shared__ unsigned short lwt[DIM * 136];  // pad 136 -> 2-way bank alias only
    int r = blockIdx.y;
    {
        const uint4* src = (const uint4*)(wt + r * DIM * DIM);
        for (int u = threadIdx.x; u < DIM * DIM / 8; u += 256) {
            int row = u >> 4, ch = u & 15;
            *(uint4*)&lwt[row * 136 + ch * 8] = src[u];
        }
    }
    __syncthreads();
    int wave = threadIdx.x >> 6, lane = threadIdx.x & 63;
    int ncol = blockIdx.x * 64 + wave * 16 + (lane & 15);
    int kg = (lane >> 4) * 8;
    int nc = ncol < NN ? ncol : NN - 1;
    const short8* xrow = (const short8*)(xb + (size_t)nc * DIM);
    short8 bfrag[4];
#pragma unroll
    for (int k = 0; k < 4; ++k) bfrag[k] = xrow[k * 4 + (lane >> 4)];
    f32x4 acc[8];
#pragma unroll
    for (int f = 0; f < 8; ++f) acc[f] = (f32x4){0.f, 0.f, 0.f, 0.f};
#pragma unroll
    for (int k = 0; k < 4; ++k) {
#pragma unroll
        for (int f = 0; f < 8; ++f) {
            short8 a = *(const short8*)&lwt[(f * 16 + (lane & 15)) * 136 + k * 32 + kg];
            acc[f] = __builtin_amdgcn_mfma_f32_16x16x32_bf16(a, bfrag[k], acc[f], 0, 0, 0);
        }
    }
    if (ncol < NN) {
        size_t base = ((size_t)r * NN + ncol) * DIM;
#pragma unroll
        for (int f = 0; f < 8; ++f) {
            uint2 v;
            v.x = (unsigned)f2bf(acc[f][0]) | ((unsigned)f2bf(acc[f][1]) << 16);
            v.y = (unsigned)f2bf(acc[f][2]) | ((unsigned)f2bf(acc[f][3]) << 16);
            *(uint2*)&wh[base + f * 16 + (lane >> 4) * 4] = v;
        }
    }
}

// --- 4. per-edge raw score + segment max + dst degree count
__global__ void k_edge_a(const int* __restrict__ tri, const float* __restrict__ ssrc,
        const float* __restrict__ sdst, float* __restrict__ eraw,
        unsigned* __restrict__ umax, int* __restrict__ cnt) {
    int e = blockIdx.x * 256 + threadIdx.x;
    int src = tri[3 * e], dst = tri[3 * e + 2];
    int rel = e / EPR;
    float er = ssrc[rel * NN + src] + sdst[rel * NN + dst];
    er = er > 0.f ? er : SLOPE * er;
    eraw[e] = er;
    atomicMax(&umax[rel * NN + dst], fkey(er));
    atomicAdd(&cnt[dst], 1);
}

// --- 5. scan (counts -> row offsets), 3 stages
__global__ void k_scan1(const int* __restrict__ cnt, int* __restrict__ excl,
                        int* __restrict__ bsum, int n) {
    __shared__ int s[256];
    int t = threadIdx.x;
    int base = blockIdx.x * 1024 + t * 4;
    int c[4];
    int sum = 0;
#pragma unroll
    for (int j = 0; j < 4; ++j) { c[j] = (base + j < n) ? cnt[base + j] : 0; sum += c[j]; }
    s[t] = sum;
    __syncthreads();
    for (int off = 1; off < 256; off <<= 1) {
        int u = t >= off ? s[t - off] : 0;
        __syncthreads();
        s[t] += u;
        __syncthreads();
    }
    int run = s[t] - sum;
#pragma unroll
    for (int j = 0; j < 4; ++j) {
        if (base + j < n) excl[base + j] = run;
        run += c[j];
    }
    if (t == 255) bsum[blockIdx.x] = s[255];
}
__global__ void k_scan2(int* bsum, int nb) {
    __shared__ int s[128];
    int t = threadIdx.x;
    int v = t < nb ? bsum[t] : 0;
    s[t] = v;
    __syncthreads();
    for (int off = 1; off < 128; off <<= 1) {
        int u = t >= off ? s[t - off] : 0;
        __syncthreads();
        s[t] += u;
        __syncthreads();
    }
    if (t < nb) bsum[t] = s[t] - v;
}
__global__ void k_scan3(int* __restrict__ rowst, const int* __restrict__ bsum,
                        int* __restrict__ cursor, int n) {
    int i = blockIdx.x * 256 + threadIdx.x;
    if (i < n) {
        int v = rowst[i] + bsum[i >> 10];
        rowst[i] = v;
        cursor[i] = v;
    }
}

// --- 6. exp + denom + CSR scatter (packed src|rel<<20 and e_exp)
__global__ void k_edge_b(const int* __restrict__ tri, const float* __restrict__ eraw,
        const unsigned* __restrict__ umax, float* __restrict__ denom,
        int* __restrict__ cursor, int* __restrict__ pmeta, float* __restrict__ pp) {
    int e = blockIdx.x * 256 + threadIdx.x;
    int src = tri[3 * e], dst = tri[3 * e + 2];
    int rel = e / EPR;
    int seg = rel * NN + dst;
    float p = __expf(eraw[e] - funkey(umax[seg]));
    atomicAdd(&denom[seg], p);
    int pos = atomicAdd(&cursor[dst], 1);
    pmeta[pos] = src | (rel << 20);
    pp[pos] = p;
}

// --- 7. per-dst aggregation: one wave per dst; gather bf16 Wh rows; +bias +residual
__global__ __launch_bounds__(256) void k_out(const int* __restrict__ rowst,
        const int* __restrict__ cnt, const int* __restrict__ pmeta,
        const float* __restrict__ pp, const float* __restrict__ denom,
        const unsigned* __restrict__ wh, const float* __restrict__ x,
        const float* __restrict__ bias, float* __restrict__ out) {
    int wave = threadIdx.x >> 6, lane = threadIdx.x & 63;
    int d = blockIdx.x * 4 + wave;
    float inv = 0.f;
    if (lane < RR) inv = 1.f / fmaxf(denom[lane * NN + d], 1e-8f);
    int start = rowst[d], c = cnt[d];
    float a0 = 0.f, a1 = 0.f;
    for (int b0 = 0; b0 < c; b0 += 64) {
        int m = 0;
        float pv = 0.f;
        if (b0 + lane < c) {
            m = pmeta[start + b0 + lane];
            pv = pp[start + b0 + lane];
        }
        int it = min(64, c - b0);
        for (int j = 0; j < it; ++j) {
            int mj = __shfl(m, j);
            float pj = __shfl(pv, j);
            float al = pj * __shfl(inv, mj >> 20);
            unsigned w = wh[((size_t)(mj >> 20) * NN + (mj & 0xFFFFF)) * 64 + lane];
            a0 = fmaf(al, __uint_as_float(w << 16), a0);
            a1 = fmaf(al, __uint_as_float(w & 0xFFFF0000u), a1);
        }
    }
    float2 xv = *(const float2*)(x + (size_t)d * DIM + lane * 2);
    float2 bv = *(const float2*)(bias + lane * 2);
    float2 ov;
    ov.x = a0 + xv.x + bv.x;
    ov.y = a1 + xv.y + bv.y;
    *(float2*)(out + (size_t)d * DIM + lane * 2) = ov;
}

extern "C" void kernel_launch(void* const* d_in, const int* in_sizes, int n_in,
                              void* d_out, int out_size, void* d_ws, size_t ws_size,
                              hipStream_t stream) {
    const float* x = (const float*)d_in[0];
    const int* tri = (const int*)d_in[1];
    const float* basis = (const float*)d_in[3];
    const float* att = (const float*)d_in[4];
    const float* attention = (const float*)d_in[5];
    const float* bias = (const float*)d_in[6];
    float* out = (float*)d_out;

    char* ws = (char*)d_ws;
    size_t off = 0;
    auto alloc = [&](size_t b) {
        char* p = ws + off;
        off = (off + b + 255) & ~(size_t)255;
        return p;
    };
    unsigned short* wh = (unsigned short*)alloc((size_t)RR * NN * DIM * 2);  // 204.8 MB
    unsigned* xb = (unsigned*)alloc((size_t)NN * DIM * 2);                   // 25.6 MB
    unsigned short* wt = (unsigned short*)alloc((size_t)RR * DIM * DIM * 2);
    float* wsrc = (float*)alloc(RR * DIM * 4);
    float* wdst = (float*)alloc(RR * DIM * 4);
    float* ssrc = (float*)alloc((size_t)RR * NN * 4);
    float* sdst = (float*)alloc((size_t)RR * NN * 4);
    float* eraw = (float*)alloc((size_t)EE * 4);
    unsigned* umax = (unsigned*)alloc((size_t)RR * NN * 4);
    float* denom = (float*)alloc((size_t)RR * NN * 4);
    int* cnt = (int*)alloc((size_t)NN * 4);
    int* rowst = (int*)alloc((size_t)NN * 4);
    int* cursor = (int*)alloc((size_t)NN * 4);
    int* bsum = (int*)alloc(4096);
    int* pmeta = (int*)alloc((size_t)EE * 4);
    float* pp = (float*)alloc((size_t)EE * 4);

    (void)hipMemsetAsync(umax, 0, (size_t)RR * NN * 4, stream);
    (void)hipMemsetAsync(denom, 0, (size_t)RR * NN * 4, stream);
    (void)hipMemsetAsync(cnt, 0, (size_t)NN * 4, stream);

    k_prep<<<RR, DIM, 0, stream>>>(att, basis, attention, wt, wsrc, wdst);
    k_scores<<<NN / 4, 256, 0, stream>>>(x, wsrc, wdst, ssrc, sdst, xb);
    k_gemm<<<dim3((NN + 63) / 64, RR), 256, 0, stream>>>(wt, (const unsigned short*)xb, wh);
    k_edge_a<<<EE / 256, 256, 0, stream>>>(tri, ssrc, sdst, eraw, umax, cnt);
    int nb = (NN + 1023) / 1024;
    k_scan1<<<nb, 256, 0, stream>>>(cnt, rowst, bsum, NN);
    k_scan2<<<1, 128, 0, stream>>>(bsum, nb);
    k_scan3<<<(NN + 255) / 256, 256, 0, stream>>>(rowst, bsum, cursor, NN);
    k_edge_b<<<EE / 256, 256, 0, stream>>>(tri, eraw, umax, denom, cursor, pmeta, pp);
    k_out<<<NN / 4, 256, 0, stream>>>(rowst, cnt, pmeta, pp, denom, (const unsigned*)wh, x,
                                      bias, out);
}